// Round 1
// baseline (775.937 us; speedup 1.0000x reference)
//
#include <hip/hip_runtime.h>
#include <hip/hip_bf16.h>

typedef __bf16 bf16x8 __attribute__((ext_vector_type(8)));
typedef float  f32x4  __attribute__((ext_vector_type(4)));

// Sizes (compile-time for this problem)
#define BATCH 2
#define SEQ   2048
#define HID   2048
#define NH    8
#define DH    256
#define LQ    2560            // QKV buffer row width: 8*256 Q + 256 K + 256 V
#define ROWS  (BATCH*SEQ)     // 4096

__device__ __forceinline__ void gld16(const void* g, void* l) {
    __builtin_amdgcn_global_load_lds(
        (__attribute__((address_space(1))) void*)(g),
        (__attribute__((address_space(3))) void*)(l), 16, 0, 0);
}

// ---------------- fp32 -> bf16 convert (vectorized) ----------------
__global__ void cvt_f32_bf16(const float* __restrict__ src, __bf16* __restrict__ dst, int n4) {
    int i = blockIdx.x * blockDim.x + threadIdx.x;
    if (i < n4) {
        float4 v = ((const float4*)src)[i];
        __bf16 o[4];
        o[0] = (__bf16)v.x; o[1] = (__bf16)v.y; o[2] = (__bf16)v.z; o[3] = (__bf16)v.w;
        ((uint2*)dst)[i] = *(uint2*)o;
    }
}

// ---------------- GEMM: C[M][N] = A[M][K] * B[N][K]^T (bf16 in, CT out) ----------------
template<typename CT>
__global__ __launch_bounds__(256)
void gemm_bt(const __bf16* __restrict__ A, const __bf16* __restrict__ B,
             CT* __restrict__ C, int M, int N, int K) {
    __shared__ __bf16 sA[128 * 32];
    __shared__ __bf16 sB[128 * 32];
    const int tid  = threadIdx.x;
    const int lane = tid & 63;
    const int wid  = tid >> 6;
    const int row0 = blockIdx.y * 128;
    const int col0 = blockIdx.x * 128;
    const int wr = (wid >> 1) * 64;
    const int wc = (wid & 1) * 64;

    // staging: chunk tid covers rows 0..63, chunk tid+256 rows 64..127 (16B each)
    const int sr0 = tid >> 2, sc0 = (tid & 3) * 8;
    const __bf16* Ag0 = A + (size_t)(row0 + sr0) * K + sc0;
    const __bf16* Ag1 = Ag0 + (size_t)64 * K;
    const __bf16* Bg0 = B + (size_t)(col0 + sr0) * K + sc0;
    const __bf16* Bg1 = Bg0 + (size_t)64 * K;
    __bf16* lA0 = &sA[wid * 512];
    __bf16* lA1 = &sA[2048 + wid * 512];
    __bf16* lB0 = &sB[wid * 512];
    __bf16* lB1 = &sB[2048 + wid * 512];

    f32x4 acc[4][4];
#pragma unroll
    for (int m = 0; m < 4; ++m)
#pragma unroll
        for (int n = 0; n < 4; ++n) acc[m][n] = (f32x4)0.f;

    for (int k0 = 0; k0 < K; k0 += 32) {
        gld16(Ag0 + k0, lA0);
        gld16(Ag1 + k0, lA1);
        gld16(Bg0 + k0, lB0);
        gld16(Bg1 + k0, lB1);
        __syncthreads();
        bf16x8 af[4], bfr[4];
#pragma unroll
        for (int m = 0; m < 4; ++m)
            af[m] = *(const bf16x8*)&sA[(wr + m * 16 + (lane & 15)) * 32 + (lane >> 4) * 8];
#pragma unroll
        for (int n = 0; n < 4; ++n)
            bfr[n] = *(const bf16x8*)&sB[(wc + n * 16 + (lane & 15)) * 32 + (lane >> 4) * 8];
#pragma unroll
        for (int m = 0; m < 4; ++m)
#pragma unroll
            for (int n = 0; n < 4; ++n)
                acc[m][n] = __builtin_amdgcn_mfma_f32_16x16x32_bf16(af[m], bfr[n], acc[m][n], 0, 0, 0);
        __syncthreads();
    }
#pragma unroll
    for (int m = 0; m < 4; ++m)
#pragma unroll
        for (int n = 0; n < 4; ++n)
#pragma unroll
            for (int r = 0; r < 4; ++r) {
                int row = row0 + wr + m * 16 + (lane >> 4) * 4 + r;
                int col = col0 + wc + n * 16 + (lane & 15);
                C[(size_t)row * N + col] = (CT)acc[m][n][r];
            }
}

// ---------------- RoPE in-place on QKV (heads 0..7 = Q, head 8 = K) ----------------
__global__ void rope_kernel(__bf16* __restrict__ QKV, const int* __restrict__ pid) {
    const int row = blockIdx.x;   // 0..4095 (= b*SEQ + s)
    const int h   = blockIdx.y;   // 0..8
    const int j   = threadIdx.x;  // 0..127
    const float pos = (float)pid[row];
    // inv_freq = 10000^(-j/128) = exp2(-j * log2(10000)/128)
    const float freq = exp2f((float)j * (-13.287712379549449f / 128.0f));
    const float ang = pos * freq;
    float sn, cs;
    sincosf(ang, &sn, &cs);
    __bf16* p = QKV + (size_t)row * LQ + h * 256 + j;
    float x1 = (float)p[0], x2 = (float)p[128];
    p[0]   = (__bf16)(x1 * cs - x2 * sn);
    p[128] = (__bf16)(x2 * cs + x1 * sn);
}

// ---------------- V transpose: QKV cols 2304.. -> Vt[B][256][SEQ] ----------------
__global__ __launch_bounds__(256)
void transpose_v(const __bf16* __restrict__ QKV, __bf16* __restrict__ Vt) {
    __shared__ __bf16 t[32][33];
    const int b  = blockIdx.z;
    const int s0 = blockIdx.x * 32;
    const int d0 = blockIdx.y * 32;
    const int c  = threadIdx.x & 31;
    const int r8 = threadIdx.x >> 5;  // 0..7
#pragma unroll
    for (int i = 0; i < 4; ++i) {
        int row = r8 + i * 8;
        t[row][c] = QKV[(size_t)(b * SEQ + s0 + row) * LQ + 2304 + d0 + c];
    }
    __syncthreads();
#pragma unroll
    for (int i = 0; i < 4; ++i) {
        int row = r8 + i * 8;
        Vt[((size_t)b * 256 + d0 + row) * SEQ + s0 + c] = t[c][row];
    }
}

// ---------------- Flash attention ----------------
// grid (S/64, B*NH), 256 thr. Wave w owns q rows [qb*64+16w, +16). K read from QKV
// (post-RoPE), V read from Vt (transposed). P bounced through per-wave LDS strip.
__global__ __launch_bounds__(256)
void attn_fwd(const __bf16* __restrict__ QKV, const __bf16* __restrict__ Vt,
              __bf16* __restrict__ O) {
    __shared__ __bf16 P[4][16 * 72];
    const int lane = threadIdx.x & 63;
    const int wid  = threadIdx.x >> 6;
    const int qb   = blockIdx.x;
    const int b    = blockIdx.y >> 3;
    const int h    = blockIdx.y & 7;
    const int l4   = lane >> 4;   // 0..3
    const int lc   = lane & 15;
    const int q0   = qb * 64 + wid * 16;

    // Q fragments: A-layout row = lc, k(d) = l4*8 + kc*32
    const __bf16* Qp = QKV + (size_t)(b * SEQ + q0 + lc) * LQ + h * 256 + l4 * 8;
    bf16x8 qf[8];
#pragma unroll
    for (int kc = 0; kc < 8; ++kc) qf[kc] = *(const bf16x8*)(Qp + kc * 32);

    f32x4 oacc[16];
#pragma unroll
    for (int i = 0; i < 16; ++i) oacc[i] = (f32x4)0.f;
    float mrow[4], lrow[4];
#pragma unroll
    for (int r = 0; r < 4; ++r) { mrow[r] = -1e30f; lrow[r] = 0.f; }

    const __bf16* Kbase = QKV + (size_t)(b * SEQ) * LQ + 2048 + l4 * 8;
    const __bf16* Vbase = Vt + (size_t)b * 256 * SEQ;
    __bf16* Pw = &P[wid][0];

    const int nt = qb + 1;
    for (int t = 0; t < nt; ++t) {
        const int kv0 = t * 64;
        f32x4 sacc[4];
#pragma unroll
        for (int ct = 0; ct < 4; ++ct) sacc[ct] = (f32x4)0.f;
#pragma unroll
        for (int ct = 0; ct < 4; ++ct) {
            const __bf16* Kp = Kbase + (size_t)(kv0 + ct * 16 + lc) * LQ;
#pragma unroll
            for (int kc = 0; kc < 8; ++kc) {
                bf16x8 kf = *(const bf16x8*)(Kp + kc * 32);
                sacc[ct] = __builtin_amdgcn_mfma_f32_16x16x32_bf16(qf[kc], kf, sacc[ct], 0, 0, 0);
            }
        }
        const bool lastt = (t == qb);
#pragma unroll
        for (int r = 0; r < 4; ++r) {
            const int qrow = q0 + l4 * 4 + r;
            float sv[4];
            float rm = -1e30f;
#pragma unroll
            for (int ct = 0; ct < 4; ++ct) {
                float s = sacc[ct][r] * 0.0625f;  // 1/sqrt(256)
                if (lastt) {
                    int col = kv0 + ct * 16 + lc;
                    if (col > qrow) s = -1e30f;
                }
                sv[ct] = s;
                rm = fmaxf(rm, s);
            }
#pragma unroll
            for (int off = 1; off < 16; off <<= 1) rm = fmaxf(rm, __shfl_xor(rm, off, 64));
            const float mnew  = fmaxf(mrow[r], rm);
            const float alpha = __expf(mrow[r] - mnew);
            mrow[r] = mnew;
            float ps = 0.f;
#pragma unroll
            for (int ct = 0; ct < 4; ++ct) {
                float p = __expf(sv[ct] - mnew);
                ps += p;
                Pw[(l4 * 4 + r) * 72 + ct * 16 + lc] = (__bf16)p;
            }
#pragma unroll
            for (int off = 1; off < 16; off <<= 1) ps += __shfl_xor(ps, off, 64);
            lrow[r] = lrow[r] * alpha + ps;
#pragma unroll
            for (int dt = 0; dt < 16; ++dt) oacc[dt][r] *= alpha;
        }
        // cross-lane LDS visibility within the wave (lockstep)
        asm volatile("s_waitcnt lgkmcnt(0)" ::: "memory");
        bf16x8 pa0 = *(const bf16x8*)&Pw[lc * 72 + l4 * 8];
        bf16x8 pa1 = *(const bf16x8*)&Pw[lc * 72 + 32 + l4 * 8];
#pragma unroll
        for (int dt = 0; dt < 16; ++dt) {
            const __bf16* Vp = Vbase + (size_t)(dt * 16 + lc) * SEQ + kv0 + l4 * 8;
            oacc[dt] = __builtin_amdgcn_mfma_f32_16x16x32_bf16(pa0, *(const bf16x8*)Vp, oacc[dt], 0, 0, 0);
            oacc[dt] = __builtin_amdgcn_mfma_f32_16x16x32_bf16(pa1, *(const bf16x8*)(Vp + 32), oacc[dt], 0, 0, 0);
        }
    }
    float inv[4];
#pragma unroll
    for (int r = 0; r < 4; ++r) inv[r] = 1.f / lrow[r];
#pragma unroll
    for (int dt = 0; dt < 16; ++dt)
#pragma unroll
        for (int r = 0; r < 4; ++r)
            O[(size_t)(b * SEQ + q0 + l4 * 4 + r) * HID + h * 256 + dt * 16 + lc] =
                (__bf16)(oacc[dt][r] * inv[r]);
}

extern "C" void kernel_launch(void* const* d_in, const int* in_sizes, int n_in,
                              void* d_out, int out_size, void* d_ws, size_t ws_size,
                              hipStream_t stream) {
    const float* hs  = (const float*)d_in[0];   // (2,2048,2048)
    const int*   pid = (const int*)d_in[1];     // (2,2048)
    // d_in[2] = attention_mask: known causal, recomputed on device
    const float* Wq  = (const float*)d_in[3];   // (2048,2048)
    const float* Wk  = (const float*)d_in[4];   // (256,2048)
    const float* Wv  = (const float*)d_in[5];   // (256,2048)
    const float* Wo  = (const float*)d_in[6];   // (2048,2048)
    float* out = (float*)d_out;

    char* ws = (char*)d_ws;
    __bf16* Xb   = (__bf16*)ws;                       // 4096x2048, also reused as attn out
    ws += (size_t)ROWS * HID * 2;
    __bf16* Wqkv = (__bf16*)ws;                       // 2560x2048
    ws += (size_t)LQ * HID * 2;
    __bf16* Wob  = (__bf16*)ws;                       // 2048x2048
    ws += (size_t)HID * HID * 2;
    __bf16* QKV  = (__bf16*)ws;                       // 4096x2560
    ws += (size_t)ROWS * LQ * 2;
    __bf16* Vt   = (__bf16*)ws;                       // 2x256x2048
    ws += (size_t)BATCH * DH * SEQ * 2;
    __bf16* Oat  = Xb;                                // alias: X dead after QKV GEMM

    // convert inputs/weights to bf16
    cvt_f32_bf16<<<(ROWS * HID / 4 + 255) / 256, 256, 0, stream>>>(hs, Xb, ROWS * HID / 4);
    cvt_f32_bf16<<<(HID * HID / 4 + 255) / 256, 256, 0, stream>>>(Wq, Wqkv, HID * HID / 4);
    cvt_f32_bf16<<<(DH * HID / 4 + 255) / 256, 256, 0, stream>>>(Wk, Wqkv + (size_t)2048 * HID, DH * HID / 4);
    cvt_f32_bf16<<<(DH * HID / 4 + 255) / 256, 256, 0, stream>>>(Wv, Wqkv + (size_t)2304 * HID, DH * HID / 4);
    cvt_f32_bf16<<<(HID * HID / 4 + 255) / 256, 256, 0, stream>>>(Wo, Wob, HID * HID / 4);

    // QKV = X @ Wqkv^T   (4096 x 2560 x 2048)
    gemm_bt<__bf16><<<dim3(LQ / 128, ROWS / 128), 256, 0, stream>>>(Xb, Wqkv, QKV, ROWS, LQ, HID);

    // RoPE in place on Q (8 heads) + K (head index 8)
    rope_kernel<<<dim3(ROWS, 9), 128, 0, stream>>>(QKV, pid);

    // V -> Vt (transposed for PV MFMA B-operand)
    transpose_v<<<dim3(SEQ / 32, DH / 32, BATCH), 256, 0, stream>>>(QKV, Vt);

    // flash attention -> Oat (4096 x 2048 bf16)
    attn_fwd<<<dim3(SEQ / 64, BATCH * NH), 256, 0, stream>>>(QKV, Vt, Oat);

    // out = Oat @ Wo^T  (4096 x 2048 x 2048, fp32 out)
    gemm_bt<float><<<dim3(HID / 128, ROWS / 128), 256, 0, stream>>>(Oat, Wob, out, ROWS, HID, HID);
}

// Round 2
// 412.808 us; speedup vs baseline: 1.8797x; 1.8797x over previous
//
#include <hip/hip_runtime.h>
#include <hip/hip_bf16.h>

typedef __bf16 bf16x8 __attribute__((ext_vector_type(8)));
typedef float  f32x4  __attribute__((ext_vector_type(4)));

#define BATCH 2
#define SEQ   2048
#define HID   2048
#define NH    8
#define DH    256
#define LQ    2560            // QKV row: 8*256 Q + 256 K + 256 V
#define ROWS  (BATCH*SEQ)     // 4096
#define KVB   32
#define NQC   128             // 16-row q-chunks per batch

__device__ __forceinline__ void gld16(const void* g, void* l) {
    __builtin_amdgcn_global_load_lds(
        (__attribute__((address_space(1))) void*)(g),
        (__attribute__((address_space(3))) void*)(l), 16, 0, 0);
}

__device__ __forceinline__ unsigned pack2bf(float a, float b) {
    union { __bf16 h[2]; unsigned u; } x;
    x.h[0] = (__bf16)a; x.h[1] = (__bf16)b;
    return x.u;
}

// ---------------- fp32 -> bf16 convert (vectorized) ----------------
__global__ void cvt_f32_bf16(const float* __restrict__ src, __bf16* __restrict__ dst, int n4) {
    int i = blockIdx.x * blockDim.x + threadIdx.x;
    if (i < n4) {
        float4 v = ((const float4*)src)[i];
        __bf16 o[4];
        o[0] = (__bf16)v.x; o[1] = (__bf16)v.y; o[2] = (__bf16)v.z; o[3] = (__bf16)v.w;
        ((uint2*)dst)[i] = *(uint2*)o;
    }
}

// ---------------- GEMM: C[M][N] = A[M][K] * B[N][K]^T (bf16 in, CT out) ----------------
template<typename CT>
__global__ __launch_bounds__(256)
void gemm_bt(const __bf16* __restrict__ A, const __bf16* __restrict__ B,
             CT* __restrict__ C, int M, int N, int K) {
    __shared__ __bf16 sA[128 * 32];
    __shared__ __bf16 sB[128 * 32];
    const int tid  = threadIdx.x;
    const int lane = tid & 63;
    const int wid  = tid >> 6;
    const int row0 = blockIdx.y * 128;
    const int col0 = blockIdx.x * 128;
    const int wr = (wid >> 1) * 64;
    const int wc = (wid & 1) * 64;

    const int sr0 = tid >> 2, sc0 = (tid & 3) * 8;
    const __bf16* Ag0 = A + (size_t)(row0 + sr0) * K + sc0;
    const __bf16* Ag1 = Ag0 + (size_t)64 * K;
    const __bf16* Bg0 = B + (size_t)(col0 + sr0) * K + sc0;
    const __bf16* Bg1 = Bg0 + (size_t)64 * K;
    __bf16* lA0 = &sA[wid * 512];
    __bf16* lA1 = &sA[2048 + wid * 512];
    __bf16* lB0 = &sB[wid * 512];
    __bf16* lB1 = &sB[2048 + wid * 512];

    f32x4 acc[4][4];
#pragma unroll
    for (int m = 0; m < 4; ++m)
#pragma unroll
        for (int n = 0; n < 4; ++n) acc[m][n] = (f32x4)0.f;

    for (int k0 = 0; k0 < K; k0 += 32) {
        gld16(Ag0 + k0, lA0);
        gld16(Ag1 + k0, lA1);
        gld16(Bg0 + k0, lB0);
        gld16(Bg1 + k0, lB1);
        __syncthreads();
        bf16x8 af[4], bfr[4];
#pragma unroll
        for (int m = 0; m < 4; ++m)
            af[m] = *(const bf16x8*)&sA[(wr + m * 16 + (lane & 15)) * 32 + (lane >> 4) * 8];
#pragma unroll
        for (int n = 0; n < 4; ++n)
            bfr[n] = *(const bf16x8*)&sB[(wc + n * 16 + (lane & 15)) * 32 + (lane >> 4) * 8];
#pragma unroll
        for (int m = 0; m < 4; ++m)
#pragma unroll
            for (int n = 0; n < 4; ++n)
                acc[m][n] = __builtin_amdgcn_mfma_f32_16x16x32_bf16(af[m], bfr[n], acc[m][n], 0, 0, 0);
        __syncthreads();
    }
#pragma unroll
    for (int m = 0; m < 4; ++m)
#pragma unroll
        for (int n = 0; n < 4; ++n)
#pragma unroll
            for (int r = 0; r < 4; ++r) {
                int row = row0 + wr + m * 16 + (lane >> 4) * 4 + r;
                int col = col0 + wc + n * 16 + (lane & 15);
                C[(size_t)row * N + col] = (CT)acc[m][n][r];
            }
}

// ---------------- RoPE in-place on QKV (heads 0..7 = Q, head 8 = K) ----------------
__global__ void rope_kernel(__bf16* __restrict__ QKV, const int* __restrict__ pid) {
    const int row = blockIdx.x;   // 0..4095
    const int h   = blockIdx.y;   // 0..8
    const int j   = threadIdx.x;  // 0..127
    const float pos = (float)pid[row];
    const float freq = exp2f((float)j * (-13.287712379549449f / 128.0f));
    const float ang = pos * freq;
    float sn, cs;
    sincosf(ang, &sn, &cs);
    __bf16* p = QKV + (size_t)row * LQ + h * 256 + j;
    float x1 = (float)p[0], x2 = (float)p[128];
    p[0]   = (__bf16)(x1 * cs - x2 * sn);
    p[128] = (__bf16)(x2 * cs + x1 * sn);
}

// ---------------- V transpose: QKV cols 2304.. -> Vt[B][256][SEQ] ----------------
__global__ __launch_bounds__(256)
void transpose_v(const __bf16* __restrict__ QKV, __bf16* __restrict__ Vt) {
    __shared__ __bf16 t[32][33];
    const int b  = blockIdx.z;
    const int s0 = blockIdx.x * 32;
    const int d0 = blockIdx.y * 32;
    const int c  = threadIdx.x & 31;
    const int r8 = threadIdx.x >> 5;
#pragma unroll
    for (int i = 0; i < 4; ++i) {
        int row = r8 + i * 8;
        t[row][c] = QKV[(size_t)(b * SEQ + s0 + row) * LQ + 2304 + d0 + c];
    }
    __syncthreads();
#pragma unroll
    for (int i = 0; i < 4; ++i) {
        int row = r8 + i * 8;
        Vt[((size_t)b * 256 + d0 + row) * SEQ + s0 + c] = t[c][row];
    }
}

// ---------------- Flash attention v2 ----------------
// 512 blocks x 128 thr (2 waves = 2 heads). Block: hg=bid&3 (heads hg*2+wid),
// p=bid>>2: b=p>>6, pr=p&63; processes paired q-chunks {pr, 127-pr} (16 rows each)
// -> uniform work. K/V double-buffered in LDS (global_load_lds w16, K XOR-swizzled).
// Swapped QK^T (mfma(K,Q)) -> lane-local softmax; P^T to PV B-frag via pack+bpermute.
__global__ __launch_bounds__(128, 2)
void attn_fwd2(const __bf16* __restrict__ QKV, const __bf16* __restrict__ Vt,
               __bf16* __restrict__ O) {
    __shared__ __bf16 Kt[2][KVB * 256];   // [kv][256d], col-bytes ^= (kv&7)<<4
    __shared__ __bf16 Vs[2][256 * KVB];   // [d][32kv], linear

    const int tid  = threadIdx.x;
    const int lane = tid & 63;
    const int wid  = tid >> 6;          // 0..1
    const int lc   = lane & 15;
    const int l4   = lane >> 4;

    const int bid = blockIdx.x;
    const int hg  = bid & 3;
    const int p   = bid >> 2;
    const int b   = p >> 6;
    const int pr  = p & 63;
    const int h   = hg * 2 + wid;

    const char* QKVb = (const char*)(QKV + (size_t)(b * SEQ) * LQ);
    const char* Kg   = QKVb + 2048 * 2;
    const char* Vg   = (const char*)(Vt + (size_t)b * DH * SEQ);

    // staging constants (per thread)
    const int krow = wid * 16 + (lane >> 5);   // + i*2   (kv row in tile)
    const int kcol = (lane & 31) * 16;         // byte col within 512B row
    const int vrow = wid * 128 + (lane >> 2);  // + i*16  (d row in tile)
    const int vcol = (lane & 3) * 16;          // byte col within 64B row

    for (int half = 0; half < 2; ++half) {
        const int qt = half ? (NQC - 1 - pr) : pr;
        const int q0 = qt * 16;
        const int nt = (qt >> 1) + 1;
        const int qrow = q0 + lc;

        // Q fragments (B-operand): col=q=lc, k(d) = l4*8 + kc*32
        const char* Qp = QKVb + (size_t)(q0 + lc) * (LQ * 2) + h * 512 + l4 * 16;
        bf16x8 qf[8];
#pragma unroll
        for (int kc = 0; kc < 8; ++kc) qf[kc] = *(const bf16x8*)(Qp + kc * 64);

        f32x4 oacc[16];
#pragma unroll
        for (int i = 0; i < 16; ++i) oacc[i] = (f32x4)0.f;
        float mrow = -1e30f, lrow = 0.f;

        // prologue: stage tile 0 into buf 0
#pragma unroll
        for (int i = 0; i < 8; ++i) {
            int r = krow + i * 2;
            gld16(Kg + (size_t)r * (LQ * 2) + (kcol ^ ((r & 7) << 4)),
                  (char*)&Kt[0][0] + wid * 8192 + i * 1024);
        }
#pragma unroll
        for (int i = 0; i < 8; ++i) {
            int r = vrow + i * 16;
            gld16(Vg + (size_t)r * (SEQ * 2) + vcol,
                  (char*)&Vs[0][0] + wid * 8192 + i * 1024);
        }

        int buf = 0;
        for (int t = 0; t < nt; ++t) {
            __syncthreads();                       // stage for t complete; prior reads done
            const int kv0 = t * KVB;
            if (t + 1 < nt) {                      // issue stage for t+1 into buf^1
                const int kvn = kv0 + KVB;
#pragma unroll
                for (int i = 0; i < 8; ++i) {
                    int r = krow + i * 2;
                    gld16(Kg + (size_t)(kvn + r) * (LQ * 2) + (kcol ^ ((r & 7) << 4)),
                          (char*)&Kt[buf ^ 1][0] + wid * 8192 + i * 1024);
                }
#pragma unroll
                for (int i = 0; i < 8; ++i) {
                    int r = vrow + i * 16;
                    gld16(Vg + (size_t)r * (SEQ * 2) + kvn * 2 + vcol,
                          (char*)&Vs[buf ^ 1][0] + wid * 8192 + i * 1024);
                }
            }

            // S^T = K * Q^T : rows kv, cols q
            f32x4 sacc[2];
            sacc[0] = (f32x4)0.f; sacc[1] = (f32x4)0.f;
            const char* Kl = (const char*)&Kt[buf][0];
#pragma unroll
            for (int ct = 0; ct < 2; ++ct) {
                const int rr = ct * 16 + lc;
                const int rbase = rr * 512;
                const int sw = (rr & 7) << 4;
#pragma unroll
                for (int kc = 0; kc < 8; ++kc) {
                    bf16x8 kf = *(const bf16x8*)(Kl + rbase + (((kc << 6) | (l4 << 4)) ^ sw));
                    sacc[ct] = __builtin_amdgcn_mfma_f32_16x16x32_bf16(kf, qf[kc], sacc[ct], 0, 0, 0);
                }
            }

            // online softmax over kv for column q=lc (lane-local + 2 shfls)
            const bool lastt = (t == nt - 1);
            float sv[2][4];
            float rm = -1e30f;
#pragma unroll
            for (int ct = 0; ct < 2; ++ct)
#pragma unroll
                for (int r = 0; r < 4; ++r) {
                    float s = sacc[ct][r] * 0.0625f;   // 1/sqrt(256)
                    if (lastt) {
                        int kv = kv0 + ct * 16 + l4 * 4 + r;
                        if (kv > qrow) s = -1e30f;
                    }
                    sv[ct][r] = s;
                    rm = fmaxf(rm, s);
                }
            rm = fmaxf(rm, __shfl_xor(rm, 16, 64));
            rm = fmaxf(rm, __shfl_xor(rm, 32, 64));
            const float mnew  = fmaxf(mrow, rm);
            const float alpha = __expf(mrow - mnew);
            mrow = mnew;
            float p0[4], p1[4], ps = 0.f;
#pragma unroll
            for (int r = 0; r < 4; ++r) { p0[r] = __expf(sv[0][r] - mnew); ps += p0[r]; }
#pragma unroll
            for (int r = 0; r < 4; ++r) { p1[r] = __expf(sv[1][r] - mnew); ps += p1[r]; }
            ps += __shfl_xor(ps, 16, 64);
            ps += __shfl_xor(ps, 32, 64);
            lrow = lrow * alpha + ps;
#pragma unroll
            for (int dt = 0; dt < 16; ++dt) {
                oacc[dt][0] *= alpha; oacc[dt][1] *= alpha;
                oacc[dt][2] *= alpha; oacc[dt][3] *= alpha;
            }

            // P^T -> PV B-frag: lane needs kv = l4*8+j at q=lc
            unsigned pkA0 = pack2bf(p0[0], p0[1]), pkA1 = pack2bf(p0[2], p0[3]);
            unsigned pkB0 = pack2bf(p1[0], p1[1]), pkB1 = pack2bf(p1[2], p1[3]);
            const int sl0 = lc + 16 * ((2 * l4) & 3);
            const int sl1 = lc + 16 * ((2 * l4 + 1) & 3);
            unsigned a0 = __shfl(pkA0, sl0, 64), a1 = __shfl(pkA1, sl0, 64);
            unsigned b0 = __shfl(pkB0, sl0, 64), b1 = __shfl(pkB1, sl0, 64);
            unsigned c0 = __shfl(pkA0, sl1, 64), c1 = __shfl(pkA1, sl1, 64);
            unsigned d0 = __shfl(pkB0, sl1, 64), d1 = __shfl(pkB1, sl1, 64);
            const bool hi = (l4 >= 2);
            union { unsigned u[4]; bf16x8 v; } pb;
            pb.u[0] = hi ? b0 : a0;
            pb.u[1] = hi ? b1 : a1;
            pb.u[2] = hi ? d0 : c0;
            pb.u[3] = hi ? d1 : c1;

            // O^T += V^T * P^T : rows d, cols q
            const char* Vl = (const char*)&Vs[buf][0];
#pragma unroll
            for (int dt = 0; dt < 16; ++dt) {
                bf16x8 vf = *(const bf16x8*)(Vl + (dt * 16 + lc) * 64 + l4 * 16);
                oacc[dt] = __builtin_amdgcn_mfma_f32_16x16x32_bf16(vf, pb.v, oacc[dt], 0, 0, 0);
            }
            buf ^= 1;
        }

        // epilogue: normalize + store (lane q=lc, d = dt*16 + l4*4 + r)
        const float inv = 1.f / lrow;
        char* Op = (char*)O + ((size_t)(b * SEQ + q0 + lc) * HID + h * 256 + l4 * 4) * 2;
#pragma unroll
        for (int dt = 0; dt < 16; ++dt) {
            __bf16 o4[4];
            o4[0] = (__bf16)(oacc[dt][0] * inv);
            o4[1] = (__bf16)(oacc[dt][1] * inv);
            o4[2] = (__bf16)(oacc[dt][2] * inv);
            o4[3] = (__bf16)(oacc[dt][3] * inv);
            *(uint2*)(Op + dt * 32) = *(uint2*)o4;
        }
        __syncthreads();   // before next half restages LDS
    }
}

extern "C" void kernel_launch(void* const* d_in, const int* in_sizes, int n_in,
                              void* d_out, int out_size, void* d_ws, size_t ws_size,
                              hipStream_t stream) {
    const float* hs  = (const float*)d_in[0];
    const int*   pid = (const int*)d_in[1];
    const float* Wq  = (const float*)d_in[3];
    const float* Wk  = (const float*)d_in[4];
    const float* Wv  = (const float*)d_in[5];
    const float* Wo  = (const float*)d_in[6];
    float* out = (float*)d_out;

    char* ws = (char*)d_ws;
    __bf16* Xb   = (__bf16*)ws;                       ws += (size_t)ROWS * HID * 2;
    __bf16* Wqkv = (__bf16*)ws;                       ws += (size_t)LQ * HID * 2;
    __bf16* Wob  = (__bf16*)ws;                       ws += (size_t)HID * HID * 2;
    __bf16* QKV  = (__bf16*)ws;                       ws += (size_t)ROWS * LQ * 2;
    __bf16* Vt   = (__bf16*)ws;                       ws += (size_t)BATCH * DH * SEQ * 2;
    __bf16* Oat  = Xb;   // alias: X dead after QKV GEMM

    cvt_f32_bf16<<<(ROWS * HID / 4 + 255) / 256, 256, 0, stream>>>(hs, Xb, ROWS * HID / 4);
    cvt_f32_bf16<<<(HID * HID / 4 + 255) / 256, 256, 0, stream>>>(Wq, Wqkv, HID * HID / 4);
    cvt_f32_bf16<<<(DH * HID / 4 + 255) / 256, 256, 0, stream>>>(Wk, Wqkv + (size_t)2048 * HID, DH * HID / 4);
    cvt_f32_bf16<<<(DH * HID / 4 + 255) / 256, 256, 0, stream>>>(Wv, Wqkv + (size_t)2304 * HID, DH * HID / 4);
    cvt_f32_bf16<<<(HID * HID / 4 + 255) / 256, 256, 0, stream>>>(Wo, Wob, HID * HID / 4);

    gemm_bt<__bf16><<<dim3(LQ / 128, ROWS / 128), 256, 0, stream>>>(Xb, Wqkv, QKV, ROWS, LQ, HID);

    rope_kernel<<<dim3(ROWS, 9), 128, 0, stream>>>(QKV, pid);

    transpose_v<<<dim3(SEQ / 32, DH / 32, BATCH), 256, 0, stream>>>(QKV, Vt);

    attn_fwd2<<<dim3(512), 128, 0, stream>>>(QKV, Vt, Oat);

    gemm_bt<float><<<dim3(HID / 128, ROWS / 128), 256, 0, stream>>>(Oat, Wob, out, ROWS, HID, HID);
}